// Round 1
// baseline (7946.657 us; speedup 1.0000x reference)
//
#include <hip/hip_runtime.h>
#include <math.h>

// Problem constants
constexpr int S_IN = 32, V_IN = 16, INVD = 16;
constexpr int S_MSG = S_IN + V_IN;           // 48
constexpr int V_MSG = S_IN + V_IN;           // 48
constexpr int NFAC  = S_MSG + V_MSG;         // 96
constexpr int S_OUT = 32, V_OUT = 16;
constexpr int OUT_PER_NODE = S_OUT + V_OUT * 3;  // 80

__device__ __forceinline__ float silu_f(float x) {
    return x / (1.0f + __expf(-x));
}

__global__ __launch_bounds__(256) void edge_kernel(
    const int*   __restrict__ esrc,
    const int*   __restrict__ edst,
    const float* __restrict__ ecut,
    const float* __restrict__ einv,
    const float* __restrict__ ns,
    const float* __restrict__ nv,
    const float* __restrict__ esh,
    const float* __restrict__ W0,
    const float* __restrict__ W1,
    const float* __restrict__ W2,
    float* __restrict__ acc_s,
    float* __restrict__ acc_v,
    int E)
{
    int e = blockIdx.x * 256 + threadIdx.x;
    if (e >= E) return;

    // ---- load edge invariants (16 floats, vectorized) ----
    float x[INVD];
    const float4* xin = reinterpret_cast<const float4*>(einv + (size_t)e * INVD);
    #pragma unroll
    for (int i = 0; i < 4; i++) {
        float4 t = xin[i];
        x[4*i+0] = t.x; x[4*i+1] = t.y; x[4*i+2] = t.z; x[4*i+3] = t.w;
    }

    constexpr float inv_s0 = 0.25f;   // 1/sqrt(16)
    constexpr float inv_s1 = 0.125f;  // 1/sqrt(64)

    // ---- layer 1: 16 -> 64 ----
    float h1[64];
    #pragma unroll
    for (int j = 0; j < 64; j++) h1[j] = 0.0f;
    #pragma unroll 4
    for (int i = 0; i < INVD; i++) {
        float xi = x[i];
        #pragma unroll
        for (int j = 0; j < 64; j++)
            h1[j] = fmaf(xi, W0[i*64 + j], h1[j]);
    }
    #pragma unroll
    for (int j = 0; j < 64; j++) h1[j] = silu_f(h1[j] * inv_s0);

    // ---- layer 2: 64 -> 64 ----
    float h2[64];
    #pragma unroll
    for (int j = 0; j < 64; j++) h2[j] = 0.0f;
    #pragma unroll 4
    for (int k = 0; k < 64; k++) {
        float hk = h1[k];
        #pragma unroll
        for (int j = 0; j < 64; j++)
            h2[j] = fmaf(hk, W1[k*64 + j], h2[j]);
    }
    #pragma unroll
    for (int j = 0; j < 64; j++) h2[j] = silu_f(h2[j] * inv_s1);

    // ---- per-edge data ----
    int s = esrc[e];
    int d = edst[e];
    float cw  = ecut[e];
    float ev0 = esh[(size_t)e*3 + 0];
    float ev1 = esh[(size_t)e*3 + 1];
    float ev2 = esh[(size_t)e*3 + 2];
    const float* nsrow = ns + (size_t)s * S_IN;
    const float* nvrow = nv + (size_t)s * (V_IN * 3);
    float* accs = acc_s + (size_t)d * S_MSG;
    float* accv = acc_v + (size_t)d * (V_MSG * 3);
    constexpr float ISQRT3 = 0.57735026918962576f;

    // ---- layer 3 (64 -> 96) in chunks of 16 cols, fused with message+scatter ----
    #pragma unroll 1
    for (int cc = 0; cc < NFAC; cc += 16) {
        float fac[16];
        #pragma unroll
        for (int c = 0; c < 16; c++) fac[c] = 0.0f;
        #pragma unroll 4
        for (int k = 0; k < 64; k++) {
            float hk = h2[k];
            #pragma unroll
            for (int c = 0; c < 16; c++)
                fac[c] = fmaf(hk, W2[k*NFAC + cc + c], fac[c]);
        }
        #pragma unroll
        for (int c = 0; c < 16; c++) {
            int col = cc + c;
            float g = fac[c] * inv_s1 * cw;
            if (col < S_MSG) {
                float val;
                if (col < V_IN) {
                    float a0 = nvrow[3*col+0], a1 = nvrow[3*col+1], a2 = nvrow[3*col+2];
                    val = (a0*ev0 + a1*ev1 + a2*ev2) * ISQRT3;
                } else {
                    val = nsrow[col - V_IN];
                }
                atomicAdd(&accs[col], val * g);
            } else {
                int r = col - S_MSG;
                if (r < S_IN) {
                    float b = nsrow[r] * g;
                    atomicAdd(&accv[3*r+0], b*ev0);
                    atomicAdd(&accv[3*r+1], b*ev1);
                    atomicAdd(&accv[3*r+2], b*ev2);
                } else {
                    int q = r - S_IN;
                    atomicAdd(&accv[3*r+0], nvrow[3*q+0] * g);
                    atomicAdd(&accv[3*r+1], nvrow[3*q+1] * g);
                    atomicAdd(&accv[3*r+2], nvrow[3*q+2] * g);
                }
            }
        }
    }
}

__global__ __launch_bounds__(256) void node_kernel(
    const float* __restrict__ acc_s,
    const float* __restrict__ acc_v,
    const float* __restrict__ WLs,
    const float* __restrict__ WLv,
    float* __restrict__ out,
    int Nn)
{
    int idx = blockIdx.x * 256 + threadIdx.x;
    if (idx >= Nn * OUT_PER_NODE) return;
    int n = idx / OUT_PER_NODE;
    int o = idx - n * OUT_PER_NODE;
    constexpr float ISQ48 = 0.14433756729740643f;  // 1/sqrt(48)
    float accum = 0.0f;
    if (o < S_OUT) {
        const float* row = acc_s + (size_t)n * S_MSG;
        #pragma unroll
        for (int c = 0; c < S_MSG; c++)
            accum = fmaf(row[c], WLs[c*S_OUT + o], accum);
    } else {
        int t = o - S_OUT;
        int r = t / 3;
        int i = t - 3*r;
        const float* row = acc_v + (size_t)n * (V_MSG * 3);
        #pragma unroll
        for (int c = 0; c < V_MSG; c++)
            accum = fmaf(row[c*3 + i], WLv[c*V_OUT + r], accum);
    }
    out[idx] = accum * ISQ48;
}

extern "C" void kernel_launch(void* const* d_in, const int* in_sizes, int n_in,
                              void* d_out, int out_size, void* d_ws, size_t ws_size,
                              hipStream_t stream) {
    const int*   esrc = (const int*)  d_in[0];
    const int*   edst = (const int*)  d_in[1];
    const float* ecut = (const float*)d_in[2];
    const float* einv = (const float*)d_in[3];
    const float* ns   = (const float*)d_in[4];
    const float* nv   = (const float*)d_in[5];
    const float* esh  = (const float*)d_in[6];
    const float* W0   = (const float*)d_in[7];
    const float* W1   = (const float*)d_in[8];
    const float* W2   = (const float*)d_in[9];
    const float* WLs  = (const float*)d_in[10];
    const float* WLv  = (const float*)d_in[11];
    float* out = (float*)d_out;

    const int E  = in_sizes[0];
    const int Nn = in_sizes[4] / S_IN;

    float* acc_s = (float*)d_ws;                       // N x 48
    float* acc_v = acc_s + (size_t)Nn * S_MSG;         // N x 48 x 3
    size_t acc_bytes = (size_t)Nn * (S_MSG + V_MSG*3) * sizeof(float);

    hipMemsetAsync(d_ws, 0, acc_bytes, stream);

    int eblocks = (E + 255) / 256;
    edge_kernel<<<eblocks, 256, 0, stream>>>(esrc, edst, ecut, einv, ns, nv, esh,
                                             W0, W1, W2, acc_s, acc_v, E);

    int nthreads = Nn * OUT_PER_NODE;
    int nblocks = (nthreads + 255) / 256;
    node_kernel<<<nblocks, 256, 0, stream>>>(acc_s, acc_v, WLs, WLv, out, Nn);
}